// Round 9
// baseline (91.638 us; speedup 1.0000x reference)
//
#include <hip/hip_runtime.h>
#include <hip/hip_bf16.h>

#define N 8192
#define D_IN 256
#define HID 512
#define Z 128
#define NCAT 16
#define EPS_F 1e-16f
#define PAD32 8960     // perm32 allocation (ints); max used 8688+64 slack
#define MAXT32 272     // max 32-row i-tiles: (8192+16*31)/32
#define JSPAN 128      // j rows per k_neg block
#define JY 8           // max j-span blocks per i-tile (covers n_c up to 1024)
#define NZERO 64       // blocks zeroing negpart

typedef short bf16x8 __attribute__((ext_vector_type(8)));
typedef float f32x4 __attribute__((ext_vector_type(4)));

__device__ __forceinline__ unsigned short f2bf(float f) {
    unsigned u = __float_as_uint(f);
    unsigned r = u + 0x7FFFu + ((u >> 16) & 1u);
    return (unsigned short)(r >> 16);
}
__device__ __forceinline__ float bf2f(unsigned short s) {
    return __uint_as_float(((unsigned)s) << 16);
}
__device__ __forceinline__ unsigned pack2(float a, float b) {
    return (unsigned)f2bf(a) | ((unsigned)f2bf(b) << 16);
}
__device__ __forceinline__ float softplus_f(float x) {
    return fmaxf(x, 0.f) + log1pf(expf(-fabsf(x)));
}

struct KParams {
    const float* x; const int* c; const float* z;
    const float* W1; const float* b1; const float* W2; const float* b2;
    const float* Wz; const float* bz; const float* ws;
    float* out;
    unsigned short *H, *fzb, *ub, *W1t, *Wzt, *wsT, *WcT;
    float *bc, *negpart;   // negpart[JY][N], per-(jspan) partial sums
    int *perm32, *cnt, *offs32, *tcat;
};

// fp32 [R][C] 32x32 tile -> bf16 transposed [C][R]
__device__ __forceinline__ void transpose32(
    const float* in, unsigned short* out, int R, int C, int r0, int c0, char* SAc) {
    float (*tile)[33] = (float (*)[33])SAc;
    int tx = threadIdx.x & 31, ty = threadIdx.x >> 5;
#pragma unroll
    for (int q = 0; q < 4; q++)
        tile[ty + 8 * q][tx] = in[(size_t)(r0 + ty + 8 * q) * C + c0 + tx];
    __syncthreads();
#pragma unroll
    for (int q = 0; q < 4; q++)
        out[(size_t)(c0 + ty + 8 * q) * R + r0 + tx] = f2bf(tile[tx][ty + 8 * q]);
}

// ================= kernel 1: transposes | bc | setup | negpart zero =================
__global__ __launch_bounds__(256) void k_prep(KParams P) {
    __shared__ char SA[4352];
    __shared__ int sTmp[128];
    int t = threadIdx.x, b = blockIdx.x;
    if (b < 128) {
        transpose32(P.W1, P.W1t, D_IN, HID, (b >> 4) * 32, (b & 15) * 32, SA);
    } else if (b < 144) {
        int q = b - 128;
        transpose32(P.Wz, P.Wzt, Z, Z, (q >> 2) * 32, (q & 3) * 32, SA);
    } else if (b < 400) {
        int q = b - 144; int m = q >> 4; q &= 15;
        transpose32(P.ws + (size_t)m * Z * Z, P.wsT + (size_t)m * Z * Z, Z, Z,
                    (q >> 2) * 32, (q & 3) * 32, SA);
    } else if (b < 416) {
        int cat = b - 400;              // bc[cat][e] = sum_d b2[d]*ws[cat][d][e]
        if (t < Z) {
            float s = 0.f;
            for (int d = 0; d < Z; d++) s += P.b2[d] * P.ws[(size_t)cat * Z * Z + d * Z + t];
            P.bc[cat * Z + t] = s;
        }
    } else if (b == 416) {
        // setup: count / scan(32-pad) / tcat / perm32 fill / pads
        for (int i = t; i < 128; i += 256) sTmp[i] = 0;
        __syncthreads();
        for (int n = t; n < N; n += 256) atomicAdd(&sTmp[(t >> 6) * 17 + P.c[n]], 1);
        __syncthreads();
        if (t < 16) {
            int s = 0;
            for (int w = 0; w < 4; w++) s += sTmp[w * 17 + t];
            sTmp[68 + t] = s;
            P.cnt[t] = s;
        }
        __syncthreads();
        if (t == 0) {
            int sp = 0;
            for (int k = 0; k < NCAT; k++) { sTmp[84 + k] = sp; sp += ((sTmp[68 + k] + 31) >> 5) << 5; }
            sTmp[100] = sp;
        }
        __syncthreads();
        if (t < 17) P.offs32[t] = sTmp[84 + t];
        for (int q = t; q < MAXT32; q += 256) {
            int cat = -1;
            for (int k = 0; k < NCAT; k++)
                if (q * 32 >= sTmp[84 + k] && q * 32 < sTmp[84 + k + 1]) cat = k;
            P.tcat[q] = cat;
        }
        if (t < 16) {                       // per-category tail pad -> -1
            for (int i = sTmp[84 + t] + sTmp[68 + t]; i < sTmp[84 + t + 1]; i++) P.perm32[i] = -1;
        }
        if (t >= 64 && t < 128) P.perm32[sTmp[100] + t - 64] = -1;   // 64 slack
        __syncthreads();
        for (int n = t; n < N; n += 256) {
            int cat = P.c[n];
            int pos = atomicAdd(&sTmp[101 + cat], 1);
            P.perm32[sTmp[84 + cat] + pos] = n;
        }
    } else {
        // zero negpart[JY][N] (grid-stride over NZERO blocks)
        for (int i = (b - 417) * 256 + t; i < JY * N; i += NZERO * 256)
            P.negpart[i] = 0.f;
    }
}

// MFMA GEMM tile: C = act(A @ Bt^T + bias), BM=128 BN=64 BK=64, 4 waves 2x2.
template<bool A_F32, bool B_F32, bool RELU>
__device__ __forceinline__ void gemm_body(
    const void* __restrict__ Ap, const void* __restrict__ Btp,
    const float* __restrict__ bias, unsigned short* __restrict__ Cb,
    int Nn, int K, int row0, int col0, char* As, char* Bs) {
    int t = threadIdx.x;
    int wave = t >> 6, l = t & 63, l15 = l & 15, lg = l >> 4;
    int wm = (wave >> 1) * 64, wn = (wave & 1) * 32;
    f32x4 acc[4][2] = {};

    for (int kk0 = 0; kk0 < K; kk0 += 64) {
#pragma unroll
        for (int q = 0; q < 4; q++) {   // A: 128 rows x 8 chunks
            int cid = t + q * 256, row = cid >> 3, ch = cid & 7;
            uint4 w;
            if (A_F32) {
                const float* g = (const float*)Ap + (size_t)(row0 + row) * K + kk0 + ch * 8;
                float4 a0 = *(const float4*)g, a1 = *(const float4*)(g + 4);
                w.x = pack2(a0.x, a0.y); w.y = pack2(a0.z, a0.w);
                w.z = pack2(a1.x, a1.y); w.w = pack2(a1.z, a1.w);
            } else {
                w = *(const uint4*)((const unsigned short*)Ap + (size_t)(row0 + row) * K + kk0 + ch * 8);
            }
            *(uint4*)(As + row * 128 + ((ch ^ (row & 7)) << 4)) = w;
        }
#pragma unroll
        for (int q = 0; q < 2; q++) {   // B: 64 rows x 8 chunks
            int cid = t + q * 256, row = cid >> 3, ch = cid & 7;
            uint4 w;
            if (B_F32) {
                const float* g = (const float*)Btp + (size_t)(col0 + row) * K + kk0 + ch * 8;
                float4 a0 = *(const float4*)g, a1 = *(const float4*)(g + 4);
                w.x = pack2(a0.x, a0.y); w.y = pack2(a0.z, a0.w);
                w.z = pack2(a1.x, a1.y); w.w = pack2(a1.z, a1.w);
            } else {
                w = *(const uint4*)((const unsigned short*)Btp + (size_t)(col0 + row) * K + kk0 + ch * 8);
            }
            *(uint4*)(Bs + row * 128 + ((ch ^ (row & 7)) << 4)) = w;
        }
        __syncthreads();
#pragma unroll
        for (int kk = 0; kk < 2; kk++) {
            int ch = kk * 4 + lg;
            bf16x8 a[4], bq[2];
#pragma unroll
            for (int m = 0; m < 4; m++) {
                int ra = wm + m * 16 + l15;
                a[m] = *(const bf16x8*)(As + ra * 128 + ((ch ^ (ra & 7)) << 4));
            }
#pragma unroll
            for (int n2 = 0; n2 < 2; n2++) {
                int rb = wn + n2 * 16 + l15;
                bq[n2] = *(const bf16x8*)(Bs + rb * 128 + ((ch ^ (rb & 7)) << 4));
            }
#pragma unroll
            for (int m = 0; m < 4; m++)
#pragma unroll
                for (int n2 = 0; n2 < 2; n2++)
                    acc[m][n2] = __builtin_amdgcn_mfma_f32_16x16x32_bf16(a[m], bq[n2], acc[m][n2], 0, 0, 0);
        }
        __syncthreads();
    }
#pragma unroll
    for (int m = 0; m < 4; m++)
#pragma unroll
        for (int n2 = 0; n2 < 2; n2++)
#pragma unroll
            for (int r = 0; r < 4; r++) {
                int row = row0 + wm + m * 16 + lg * 4 + r;
                int col = col0 + wn + n2 * 16 + l15;
                float v = acc[m][n2][r] + (bias ? bias[col] : 0.f);
                if (RELU) v = fmaxf(v, 0.f);
                Cb[(size_t)row * Nn + col] = f2bf(v);
            }
}

// ================= kernel 2: gemm1(H) | fz | WcT =================
__global__ __launch_bounds__(256, 3) void k_mid(KParams P) {
    __shared__ char SA[16384];
    __shared__ char SB[16384];
    int b = blockIdx.x;
    if (b < 512) {
        gemm_body<true, false, true>(P.x, P.W1t, P.b1, P.H, HID, D_IN,
                                     (b >> 3) * 128, (b & 7) * 64, SA, SB);
    } else if (b < 640) {
        int q = b - 512;
        gemm_body<true, false, false>(P.z, P.Wzt, P.bz, P.fzb, Z, Z,
                                      (q >> 1) * 128, (q & 1) * 64, SA, SB);
    } else {
        int q = b - 640; int cat = q >> 3;
        gemm_body<false, true, false>(P.wsT + (size_t)cat * Z * Z, P.W2, nullptr,
                                      P.WcT + (size_t)cat * Z * HID, HID, Z,
                                      0, (q & 7) * 64, SA, SB);
    }
}

// ================= kernel 3: ub[perm32 rows] = H @ WcT[cat]^T + bc ==============
// grid (2, MAXT32): 32-row i-tile x 64-col half, K=512.
__global__ __launch_bounds__(256, 4) void k_u(KParams P) {
    __shared__ char SA[4096];      // 32 rows x 128B (bf16 x 64k), swizzled
    __shared__ char SB[8192];      // 64 cols x 128B
    __shared__ int sIp[32];
    int t = threadIdx.x, it = blockIdx.y, jn = blockIdx.x;
    int cat = P.tcat[it];
    if (cat < 0) return;
    int ibase = it * 32;
    if (t < 32) sIp[t] = P.perm32[ibase + t];
    __syncthreads();
    const unsigned short* Wc = P.WcT + (size_t)cat * Z * HID + (size_t)jn * 64 * HID;
    int wv = t >> 6, l15 = t & 15, lg = (t & 63) >> 4;
    f32x4 acc[2] = {};
    for (int kk0 = 0; kk0 < HID; kk0 += 64) {
        {
            int row = t >> 3, ch = t & 7;
            int pi = sIp[row];
            uint4 w = make_uint4(0, 0, 0, 0);
            if (pi >= 0) w = *(const uint4*)(P.H + (size_t)pi * HID + kk0 + ch * 8);
            *(uint4*)(SA + row * 128 + ((ch ^ (row & 7)) << 4)) = w;
        }
#pragma unroll
        for (int q = 0; q < 2; q++) {
            int cid = t + q * 256, row = cid >> 3, ch = cid & 7;
            uint4 w = *(const uint4*)(Wc + (size_t)row * HID + kk0 + ch * 8);
            *(uint4*)(SB + row * 128 + ((ch ^ (row & 7)) << 4)) = w;
        }
        __syncthreads();
#pragma unroll
        for (int kk = 0; kk < 2; kk++) {
            int ch = kk * 4 + lg;
            int ra0 = l15, ra1 = 16 + l15, rb = wv * 16 + l15;
            bf16x8 a0 = *(const bf16x8*)(SA + ra0 * 128 + ((ch ^ (ra0 & 7)) << 4));
            bf16x8 a1 = *(const bf16x8*)(SA + ra1 * 128 + ((ch ^ (ra1 & 7)) << 4));
            bf16x8 bb = *(const bf16x8*)(SB + rb * 128 + ((ch ^ (rb & 7)) << 4));
            acc[0] = __builtin_amdgcn_mfma_f32_16x16x32_bf16(a0, bb, acc[0], 0, 0, 0);
            acc[1] = __builtin_amdgcn_mfma_f32_16x16x32_bf16(a1, bb, acc[1], 0, 0, 0);
        }
        __syncthreads();
    }
#pragma unroll
    for (int m = 0; m < 2; m++)
#pragma unroll
        for (int r = 0; r < 4; r++) {
            int pi = sIp[m * 16 + lg * 4 + r];
            int col = jn * 64 + wv * 16 + l15;
            if (pi >= 0) P.ub[(size_t)pi * Z + col] = f2bf(acc[m][r] + P.bc[cat * Z + col]);
        }
}

// ================= kernel 4: neg partials, (i-tile 32) x (j-span 128), no atomics ==
__global__ __launch_bounds__(256, 4) void k_neg(KParams P) {
    __shared__ char UL[8192];      // u i-tile bf16 [32][128], swizzled
    __shared__ char SB[16384];     // fz j-chunk bf16 [64][128], swizzled
    __shared__ int sIp[32];
    __shared__ int jp[64];
    __shared__ float negw[4][32];
    int t = threadIdx.x, it = blockIdx.y;
    int cat = P.tcat[it];
    if (cat < 0) return;
    int jbase0 = P.offs32[cat], jend = P.offs32[cat + 1];
    int jlo = jbase0 + blockIdx.x * JSPAN;
    if (jlo >= jend) return;
    int jhi = min(jlo + JSPAN, jend);
    int ibase = it * 32;
    int wv = t >> 6, l15 = t & 15, lg = (t & 63) >> 4;
    if (t < 32) sIp[t] = P.perm32[ibase + t];
    __syncthreads();
#pragma unroll
    for (int q = 0; q < 2; q++) {
        int cid = t + q * 256, row = cid >> 4, ch = cid & 15;
        int pi = sIp[row];
        uint4 w = make_uint4(0, 0, 0, 0);
        if (pi >= 0) w = *(const uint4*)(P.ub + (size_t)pi * Z + ch * 8);
        *(uint4*)(UL + row * 256 + ((ch ^ (row & 7)) << 4)) = w;
    }
    float rsum[2][4] = {};
    for (int jb = jlo; jb < jhi; jb += 64) {
        __syncthreads();
#pragma unroll
        for (int q = 0; q < 4; q++) {
            int cid = t + q * 256, row = cid >> 4, ch = cid & 15;
            int jidx = jb + row;
            int pj = (jidx < jend) ? P.perm32[jidx] : -1;
            uint4 w = make_uint4(0, 0, 0, 0);
            if (pj >= 0) w = *(const uint4*)(P.fzb + (size_t)pj * Z + ch * 8);
            *(uint4*)(SB + row * 256 + ((ch ^ (row & 7)) << 4)) = w;
            if (ch == 0) jp[row] = pj;
        }
        __syncthreads();
        f32x4 a2[2] = {};
#pragma unroll
        for (int kk = 0; kk < 4; kk++) {
            int ch = kk * 4 + lg;
            int ra0 = l15, ra1 = 16 + l15, rb = wv * 16 + l15;
            bf16x8 a0 = *(const bf16x8*)(UL + ra0 * 256 + ((ch ^ (ra0 & 7)) << 4));
            bf16x8 a1 = *(const bf16x8*)(UL + ra1 * 256 + ((ch ^ (ra1 & 7)) << 4));
            bf16x8 bb = *(const bf16x8*)(SB + rb * 256 + ((ch ^ (rb & 7)) << 4));
            a2[0] = __builtin_amdgcn_mfma_f32_16x16x32_bf16(a0, bb, a2[0], 0, 0, 0);
            a2[1] = __builtin_amdgcn_mfma_f32_16x16x32_bf16(a1, bb, a2[1], 0, 0, 0);
        }
        bool jv = jp[wv * 16 + l15] >= 0;
#pragma unroll
        for (int m = 0; m < 2; m++)
#pragma unroll
            for (int r = 0; r < 4; r++)
                rsum[m][r] += jv ? softplus_f(a2[m][r]) : 0.f;
    }
#pragma unroll
    for (int m = 0; m < 2; m++)
#pragma unroll
        for (int r = 0; r < 4; r++) {
            float v = rsum[m][r];
            v += __shfl_xor(v, 1, 16);
            v += __shfl_xor(v, 2, 16);
            v += __shfl_xor(v, 4, 16);
            v += __shfl_xor(v, 8, 16);
            if (l15 == 0) negw[wv][m * 16 + lg * 4 + r] = v;
        }
    __syncthreads();
    if (t < 32) {
        int pi = sIp[t];
        if (pi >= 0) {
            float ns = negw[0][t] + negw[1][t] + negw[2][t] + negw[3][t];
            P.negpart[(size_t)blockIdx.x * N + pi] = ns;   // unique slot, no atomic
        }
    }
}

// ================= kernel 5: out = log(softplus(u.fz)+eps) - log(neg_T+eps) ======
__global__ __launch_bounds__(256) void k_final(KParams P) {
    int gid = blockIdx.x * 256 + threadIdx.x;
    int n = gid >> 3, l8 = gid & 7;
    if (n >= N) return;
    float dot = 0.f;
#pragma unroll
    for (int j = 0; j < 2; j++) {
        int ch = l8 * 2 + j;
        bf16x8 uu = *(const bf16x8*)(P.ub + (size_t)n * Z + ch * 8);
        bf16x8 ff = *(const bf16x8*)(P.fzb + (size_t)n * Z + ch * 8);
#pragma unroll
        for (int e = 0; e < 8; e++)
            dot += bf2f((unsigned short)uu[e]) * bf2f((unsigned short)ff[e]);
    }
    dot += __shfl_xor(dot, 1, 8);
    dot += __shfl_xor(dot, 2, 8);
    dot += __shfl_xor(dot, 4, 8);
    if (l8 == 0) {
        float ns = 0.f;
#pragma unroll
        for (int q = 0; q < JY; q++) ns += P.negpart[(size_t)q * N + n];
        float T = softplus_f(dot);
        float nT = ns / (float)P.cnt[P.c[n]];
        P.out[n] = logf(T + EPS_F) - logf(nT + EPS_F);
    }
}

extern "C" void kernel_launch(void* const* d_in, const int* in_sizes, int n_in,
                              void* d_out, int out_size, void* d_ws, size_t ws_size,
                              hipStream_t stream) {
    KParams P;
    P.x  = (const float*)d_in[0];
    P.c  = (const int*)d_in[1];
    P.z  = (const float*)d_in[2];
    P.W1 = (const float*)d_in[3];
    P.b1 = (const float*)d_in[4];
    P.W2 = (const float*)d_in[5];
    P.b2 = (const float*)d_in[6];
    P.Wz = (const float*)d_in[7];
    P.bz = (const float*)d_in[8];
    P.ws = (const float*)d_in[9];
    P.out = (float*)d_out;

    char* p = (char*)d_ws;
    P.H    = (unsigned short*)p; p += (size_t)N * HID * 2;
    P.fzb  = (unsigned short*)p; p += (size_t)N * Z * 2;
    P.ub   = (unsigned short*)p; p += (size_t)N * Z * 2;
    P.W1t  = (unsigned short*)p; p += (size_t)D_IN * HID * 2;
    P.Wzt  = (unsigned short*)p; p += (size_t)Z * Z * 2;
    P.wsT  = (unsigned short*)p; p += (size_t)NCAT * Z * Z * 2;
    P.WcT  = (unsigned short*)p; p += (size_t)NCAT * Z * HID * 2;
    P.bc   = (float*)p;          p += (size_t)NCAT * Z * 4;
    P.negpart = (float*)p;       p += (size_t)JY * N * 4;
    P.perm32  = (int*)p;         p += (size_t)PAD32 * 4;
    P.cnt     = (int*)p;         p += 256;
    P.offs32  = (int*)p;         p += 256;
    P.tcat    = (int*)p;         p += 2048;

    k_prep<<<dim3(417 + NZERO), dim3(256), 0, stream>>>(P);
    k_mid<<<dim3(768), dim3(256), 0, stream>>>(P);
    k_u<<<dim3(2, MAXT32), dim3(256), 0, stream>>>(P);
    k_neg<<<dim3(JY, MAXT32), dim3(256), 0, stream>>>(P);
    k_final<<<dim3(N * 8 / 256), dim3(256), 0, stream>>>(P);
}